// Round 13
// baseline (181.511 us; speedup 1.0000x reference)
//
#include <hip/hip_runtime.h>
#include <hip/hip_bf16.h>

// Performer FastAttention — MFMA bf16 (consistent bf16 rounding).
// Keys: BARRIER-FREE, LDS-FREE — per-lane direct global operands (k rows,
// v column-gather), diag folded into S-GEMM via an extra MFMA k-slice with
// (diag_hi,diag_lo)x(-1,-1). Partials to d_out + reduce. Query: single-pass
// unshifted-exp with eps-correction (unchanged from r12).
// B=4,H=16 -> BH=64; N=4096; D=E=64; M=256.

#define BH    64
#define NSEQ  4096
#define DD    64
#define MM    256
#define DN    0.35355339059327373f   // 64^-0.25
#define RATIO 0.0625f                 // 256^-0.5
#define EPS   1e-4f
#define NSEG  8

// ws layout (float units) — proven 4.28 MB layout:
#define CTX_OFF  0                       // BH*MM*DD = 1,048,576
#define KSUM_OFF (BH*MM*DD)              // + BH*MM = 16,384
#define VSUM_OFF (KSUM_OFF + BH*MM)      // + BH*DD = 4,096
#define MG_OFF   (VSUM_OFF + BH*DD)      // + 4
#define CTX_SLICE (BH*MM*DD)             // per-seg partial slice (in d_out)

typedef __attribute__((ext_vector_type(8)))  short bf16x8;
typedef __attribute__((ext_vector_type(16))) float f32x16;

#define MFMA(a,b,c) __builtin_amdgcn_mfma_f32_32x32x16_bf16((a),(b),(c),0,0,0)
#define PATROW(r,h) ((((r)&3) + 8*((r)>>2)) + 4*(h))

__device__ __forceinline__ unsigned pkbf(float lo, float hi) {
    union { __hip_bfloat162 b2; unsigned u; } cvt;
    cvt.b2 = __float22bfloat162_rn(make_float2(lo, hi));
    return cvt.u;
}
// 8 floats -> bf16x8 via 4x v_cvt_pk_bf16_f32
__device__ __forceinline__ bf16x8 hi8(const float* x) {
    union { unsigned w[4]; bf16x8 v; } r;
    r.w[0] = pkbf(x[0], x[1]);
    r.w[1] = pkbf(x[2], x[3]);
    r.w[2] = pkbf(x[4], x[5]);
    r.w[3] = pkbf(x[6], x[7]);
    return r.v;
}
__device__ __forceinline__ unsigned short f2bf(float x) {
    unsigned u = __float_as_uint(x);
    return (unsigned short)((u + 0x7fffu + ((u >> 16) & 1u)) >> 16);
}
__device__ __forceinline__ unsigned ford(float f) {
    unsigned u = __float_as_uint(f);
    return (u & 0x80000000u) ? ~u : (u | 0x80000000u);
}
__device__ __forceinline__ float ford_inv(unsigned u) {
    return (u & 0x80000000u) ? __uint_as_float(u & 0x7fffffffu) : __uint_as_float(~u);
}
// C-layout tile (16 f32, rows = PATROW(r,h), col = l31) -> A-operand bf16 fragment.
template<int BASE>
__device__ __forceinline__ bf16x8 repack8(const f32x16& a, int h) {
    unsigned X0 = pkbf(a[BASE+0], a[BASE+1]);
    unsigned X1 = pkbf(a[BASE+2], a[BASE+3]);
    unsigned Y0 = pkbf(a[BASE+4], a[BASE+5]);
    unsigned Y1 = pkbf(a[BASE+6], a[BASE+7]);
    unsigned tX0 = (unsigned)__shfl_xor((int)X0, 32);
    unsigned tX1 = (unsigned)__shfl_xor((int)X1, 32);
    unsigned tY0 = (unsigned)__shfl_xor((int)Y0, 32);
    unsigned tY1 = (unsigned)__shfl_xor((int)Y1, 32);
    union { unsigned w[4]; bf16x8 v; } r;
    r.w[0] = h ? tY0 : X0;
    r.w[1] = h ? tY1 : X1;
    r.w[2] = h ? Y0 : tX0;
    r.w[3] = h ? Y1 : tX1;
    return r.v;
}

// ============================ KEYS ============================
// grid 512 = bh(64) x seg(8); block 512 = 8 waves; 8 chunks x 64 k-rows.
// NO LDS, NO barriers. Wave owns m-tile (32*wv..+31); per chunk it holds all
// 64 n-rows of S in registers, repacks in-reg, contracts ctx itself.
__global__ __launch_bounds__(512, 2)
void keys_kernel(const float* __restrict__ kg, const float* __restrict__ vg,
                 const float* __restrict__ pg, float* __restrict__ ws,
                 float* __restrict__ outp)
{
    const int tid  = threadIdx.x;
    const int wv   = tid >> 6;
    const int lane = tid & 63;
    const int l31  = lane & 31;
    const int h    = lane >> 5;
    const int bh   = blockIdx.x >> 3;
    const int seg  = blockIdx.x & 7;

    // proj B-fragments (col m = 32*wv + l31), DN folded, bf16
    bf16x8 pBh[4];
    {
        const int m = 32*wv + l31;
#pragma unroll
        for (int ks = 0; ks < 4; ++ks) {
            const int d0 = 16*ks + 8*h;
            float x[8];
            *(float4*)&x[0] = *(const float4*)(pg + m*64 + d0);
            *(float4*)&x[4] = *(const float4*)(pg + m*64 + d0 + 4);
#pragma unroll
            for (int i = 0; i < 8; ++i) x[i] *= DN;
            pBh[ks] = hi8(x);
        }
    }

    // constant B-fragment for the diag-subtract MFMA: B[k64]=-1, B[k65]=-1
    union { unsigned w[4]; bf16x8 v; } dBu;
    dBu.w[0] = h ? 0u : 0xBF80BF80u;
    dBu.w[1] = 0u; dBu.w[2] = 0u; dBu.w[3] = 0u;
    const bf16x8 dB = dBu.v;

    f32x16 cacc0, cacc1;
#pragma unroll
    for (int i = 0; i < 16; ++i) { cacc0[i] = 0.f; cacc1[i] = 0.f; }
    float ksacc = 0.f, mloc = -3e38f, vs0 = 0.f, vs1 = 0.f;

    for (int ch = 0; ch < 8; ++ch) {
        const int rowb = bh*NSEQ + seg*512 + ch*64;

        // ---- k A-fragments: per-lane rows l31 / l31+32, plus ss for diag ----
        bf16x8 ka0[4], ka1[4];
        float ss0 = 0.f, ss1 = 0.f;
#pragma unroll
        for (int ks = 0; ks < 4; ++ks) {
            const size_t a0 = ((size_t)(rowb + l31)) * 64 + 16*ks + 8*h;
            const size_t a1 = ((size_t)(rowb + l31 + 32)) * 64 + 16*ks + 8*h;
            float x0[8], x1[8];
            *(float4*)&x0[0] = *(const float4*)(kg + a0);
            *(float4*)&x0[4] = *(const float4*)(kg + a0 + 4);
            *(float4*)&x1[0] = *(const float4*)(kg + a1);
            *(float4*)&x1[4] = *(const float4*)(kg + a1 + 4);
#pragma unroll
            for (int i = 0; i < 8; ++i) {
                ss0 = fmaf(x0[i], x0[i], ss0);
                ss1 = fmaf(x1[i], x1[i], ss1);
            }
            ka0[ks] = hi8(x0);
            ka1[ks] = hi8(x1);
        }
        // diag (lane-local after h-exchange): 0.5*DN^2 = 1/16
        const float diag0 = (ss0 + __shfl_xor(ss0, 32)) * 0.0625f;
        const float diag1 = (ss1 + __shfl_xor(ss1, 32)) * 0.0625f;

        // ---- S-GEMM: D[n][m], 8 MFMAs ----
        f32x16 s0, s1;
#pragma unroll
        for (int i = 0; i < 16; ++i) { s0[i] = 0.f; s1[i] = 0.f; }
#pragma unroll
        for (int ks = 0; ks < 4; ++ks) {
            s0 = MFMA(ka0[ks], pBh[ks], s0);
            s1 = MFMA(ka1[ks], pBh[ks], s1);
        }

        // ---- v B-fragments: per-lane column gather (cols l31, l31+32) ----
        bf16x8 vb0[4], vb1[4];
#pragma unroll
        for (int kss = 0; kss < 4; ++kss) {
            const size_t vbse = ((size_t)(rowb + 16*kss + 8*h)) * 64;
            float y0[8], y1[8];
#pragma unroll
            for (int j = 0; j < 8; ++j) {
                y0[j] = vg[vbse + (size_t)j*64 + l31];
                y1[j] = vg[vbse + (size_t)j*64 + l31 + 32];
            }
#pragma unroll
            for (int j = 0; j < 8; ++j) { vs0 += y0[j]; vs1 += y1[j]; }
            vb0[kss] = hi8(y0);
            vb1[kss] = hi8(y1);
        }

        // ---- global max scan (over kd, BEFORE diag subtract) ----
#pragma unroll
        for (int r = 0; r < 16; ++r) {
            mloc = fmaxf(mloc, s0[r]);
            mloc = fmaxf(mloc, s1[r]);
        }

        // ---- diag subtract via one MFMA per n-tile (hi/lo split, exact-ish) ----
        {
            const float dh0 = __uint_as_float((unsigned)f2bf(diag0) << 16);
            const float dh1 = __uint_as_float((unsigned)f2bf(diag1) << 16);
            union { unsigned w[4]; bf16x8 v; } dA0, dA1;
            dA0.w[0] = h ? 0u : pkbf(diag0, diag0 - dh0);
            dA1.w[0] = h ? 0u : pkbf(diag1, diag1 - dh1);
            dA0.w[1] = 0u; dA0.w[2] = 0u; dA0.w[3] = 0u;
            dA1.w[1] = 0u; dA1.w[2] = 0u; dA1.w[3] = 0u;
            s0 = MFMA(dA0.v, dB, s0);
            s1 = MFMA(dA1.v, dB, s1);
        }

        // ---- w = exp(S - diag), ksum ----
        {
            float kp = 0.f;
#pragma unroll
            for (int r = 0; r < 16; ++r) {
                const float w0 = __expf(s0[r]); s0[r] = w0; kp += w0;
                const float w1 = __expf(s1[r]); s1[r] = w1; kp += w1;
            }
            ksacc += kp;
        }

        // ---- repack + ctx GEMM (interleaved to limit live registers) ----
        {
            bf16x8 t;
            t = repack8<0>(s0, h);
            cacc0 = MFMA(t, vb0[0], cacc0);
            cacc1 = MFMA(t, vb1[0], cacc1);
            t = repack8<8>(s0, h);
            cacc0 = MFMA(t, vb0[1], cacc0);
            cacc1 = MFMA(t, vb1[1], cacc1);
            t = repack8<0>(s1, h);
            cacc0 = MFMA(t, vb0[2], cacc0);
            cacc1 = MFMA(t, vb1[2], cacc1);
            t = repack8<8>(s1, h);
            cacc0 = MFMA(t, vb0[3], cacc0);
            cacc1 = MFMA(t, vb1[3], cacc1);
        }
    }

    // ---- finals (no LDS, no barrier) ----
    ksacc += __shfl_xor(ksacc, 32);
    if (h == 0) atomicAdd(&ws[KSUM_OFF + bh*MM + 32*wv + l31], ksacc);

#pragma unroll
    for (int m = 1; m <= 32; m <<= 1) mloc = fmaxf(mloc, __shfl_xor(mloc, m));
    if (lane == 0) atomicMax((unsigned*)&ws[MG_OFF], ford(mloc));

    // ctx partial slice: plain coalesced stores into d_out scratch
    {
        float* cb = outp + (size_t)(seg*BH + bh) * (MM*DD);
#pragma unroll
        for (int r = 0; r < 16; ++r) {
            const int m = 32*wv + PATROW(r, h);
            cb[m*64 + l31]      = cacc0[r];
            cb[m*64 + l31 + 32] = cacc1[r];
        }
    }

    // vsum: all waves computed identical partials (same v data); wave 0 writes.
    vs0 += __shfl_xor(vs0, 32);
    vs1 += __shfl_xor(vs1, 32);
    if (wv == 0 && h == 0) {
        atomicAdd(&ws[VSUM_OFF + bh*DD + l31],      vs0);
        atomicAdd(&ws[VSUM_OFF + bh*DD + l31 + 32], vs1);
    }
}

// ============================ REDUCE ============================
__global__ __launch_bounds__(512)
void reduce_kernel(const float* __restrict__ outp, float* __restrict__ ws)
{
    const int idx = blockIdx.x * 512 + threadIdx.x;
    const float4* o4 = (const float4*)outp;
    float4 s = o4[idx];
#pragma unroll
    for (int sl = 1; sl < NSEG; ++sl) {
        float4 t = o4[sl*(CTX_SLICE/4) + idx];
        s.x += t.x; s.y += t.y; s.z += t.z; s.w += t.w;
    }
    ((float4*)(ws + CTX_OFF))[idx] = s;
}

// ============================ QUERY ============================
// grid 512 = bh(64) x seg(8); block 512 = 8 waves; 2 chunks x 256 q-rows.
__global__ __launch_bounds__(512, 2)
void query_kernel(const float* __restrict__ qg, const float* __restrict__ pg,
                  const float* __restrict__ ws, float* __restrict__ out)
{
    __shared__ __align__(16) short pfh[MM*DD];      // DN-folded proj, frag-grouped
    __shared__ __align__(16) short ctxb[32*64*8];   // (ksg*2+h) x ecol x j
    __shared__ float ksuml[MM];
    __shared__ float ctxsuml[DD];
    __shared__ float ksumsuml;
    __shared__ float epsl[8][32];
    __shared__ float denl[8][32];

    const int tid  = threadIdx.x;
    const int wv   = tid >> 6;
    const int lane = tid & 63;
    const int l31  = lane & 31;
    const int h    = lane >> 5;
    const int bh   = blockIdx.x >> 3;
    const int seg  = blockIdx.x & 7;

    const float mg = ford_inv(*(const unsigned*)&ws[MG_OFF]);
    const float cs = RATIO * __expf(-mg);
    const float ce = RATIO * EPS;

    if (tid < DD) ctxsuml[tid] = 0.f;
    if (tid == 0) ksumsuml = 0.f;
    __syncthreads();

    // proj staging (DN folded) -> frag-grouped LDS
    {
        const int m = tid >> 1, dh = tid & 1;
#pragma unroll
        for (int b = 0; b < 4; ++b) {
            const int d0 = dh*32 + b*8;
            float x[8];
            *(float4*)&x[0] = *(const float4*)(pg + m*64 + d0);
            *(float4*)&x[4] = *(const float4*)(pg + m*64 + d0 + 4);
#pragma unroll
            for (int i = 0; i < 8; ++i) x[i] *= DN;
            const int g = ((m>>5)*4 + (d0>>4))*2 + ((d0>>3)&1);
            *(bf16x8*)&pfh[(g*32 + (m&31))*8] = hi8(x);
        }
    }
    // ctx staging: fold cs/ce, bf16, frag-grouped; accumulate ctxsum
#pragma unroll
    for (int it = 0; it < 4; ++it) {
        const int gid = it*512 + tid;
        const int g = gid >> 6, e = gid & 63;
        const int mb = (g>>1)*16 + (g&1)*8;
        const float vs = ws[VSUM_OFF + bh*DD + e];
        float part = 0.f;
        float xv[8];
#pragma unroll
        for (int j = 0; j < 8; ++j) {
            xv[j] = cs*ws[CTX_OFF + (size_t)bh*(MM*DD) + (mb+j)*64 + e] + ce*vs;
            part += xv[j];
        }
        *(bf16x8*)&ctxb[(g*64 + e)*8] = hi8(xv);
        atomicAdd(&ctxsuml[e], part);
    }
    // ksum (f32) + ksumsum
    if (tid < 256) {
        const float kt = cs*ws[KSUM_OFF + bh*MM + tid] + ce*(float)NSEQ;
        ksuml[tid] = kt;
        atomicAdd(&ksumsuml, kt);
    }
    __syncthreads();

    const float cs0 = ctxsuml[l31];
    const float cs1 = ctxsuml[l31 + 32];
    const float kss = ksumsuml;

    for (int ch = 0; ch < 2; ++ch) {
        const int rown = seg*512 + ch*256 + wv*32;
        const size_t gn = (size_t)(bh*NSEQ + rown + l31);

        // q straight from global (raw bf16); diag = ss/16
        bf16x8 qbh[4];
        float ss = 0.f;
#pragma unroll
        for (int ks = 0; ks < 4; ++ks) {
            const int d0 = 16*ks + 8*h;
            float x[8];
            *(float4*)&x[0] = *(const float4*)(qg + gn*64 + d0);
            *(float4*)&x[4] = *(const float4*)(qg + gn*64 + d0 + 4);
#pragma unroll
            for (int i = 0; i < 8; ++i) ss = fmaf(x[i], x[i], ss);
            qbh[ks] = hi8(x);
        }
        const float diag = (ss + __shfl_xor(ss, 32)) * 0.0625f;

        // ---- fused: S tile -> u=exp(S-diag) -> max/den -> repack -> num GEMM ----
        f32x16 n0, n1;
#pragma unroll
        for (int i = 0; i < 16; ++i) { n0[i] = 0.f; n1[i] = 0.f; }
        float den = 0.f, mx = -3e38f;
#pragma unroll
        for (int mt = 0; mt < 8; ++mt) {
            f32x16 s;
#pragma unroll
            for (int i = 0; i < 16; ++i) s[i] = 0.f;
#pragma unroll
            for (int ks = 0; ks < 4; ++ks) {
                const int g = (mt*4 + ks)*2 + h;
                bf16x8 ah = *(const bf16x8*)&pfh[(g*32 + l31)*8];
                s = MFMA(ah, qbh[ks], s);
            }
#pragma unroll
            for (int r = 0; r < 16; ++r) mx = fmaxf(mx, s[r]);
#pragma unroll
            for (int r = 0; r < 16; ++r) {
                const float u = __expf(s[r] - diag);
                s[r] = u;
                den = fmaf(u, ksuml[mt*32 + PATROW(r, h)], den);
            }
            bf16x8 t0 = repack8<0>(s, h);
            bf16x8 t1 = repack8<8>(s, h);
            const int g0 = 4*mt + h, g1 = 4*mt + 2 + h;
            n0 = MFMA(t0, *(const bf16x8*)&ctxb[(g0*64 + l31)*8],      n0);
            n1 = MFMA(t0, *(const bf16x8*)&ctxb[(g0*64 + l31 + 32)*8], n1);
            n0 = MFMA(t1, *(const bf16x8*)&ctxb[(g1*64 + l31)*8],      n0);
            n1 = MFMA(t1, *(const bf16x8*)&ctxb[(g1*64 + l31 + 32)*8], n1);
        }

        // combine h-halves for this lane's own row (col l31)
        mx  = fmaxf(mx, __shfl_xor(mx, 32));
        den += __shfl_xor(den, 32);
        const float epsp = EPS * __expf(mx);
        const float denf = den + epsp * kss;
        if (h == 0) { epsl[wv][l31] = epsp; denl[wv][l31] = denf; }
        asm volatile("s_waitcnt lgkmcnt(0)" ::: "memory");

        // out = (num + eps*e^m*ctxsum) / den
#pragma unroll
        for (int r = 0; r < 16; ++r) {
            const int nn = PATROW(r, h);
            const float e1  = epsl[wv][nn];
            const float rdn = 1.0f / denl[wv][nn];
            float* op = out + ((size_t)(bh*NSEQ + rown + nn))*64;
            op[l31]      = (n0[r] + e1*cs0) * rdn;
            op[l31 + 32] = (n1[r] + e1*cs1) * rdn;
        }
    }
}

extern "C" void kernel_launch(void* const* d_in, const int* in_sizes, int n_in,
                              void* d_out, int out_size, void* d_ws, size_t ws_size,
                              hipStream_t stream)
{
    const float* q = (const float*)d_in[0];
    const float* k = (const float*)d_in[1];
    const float* v = (const float*)d_in[2];
    const float* p = (const float*)d_in[3];
    float* ws  = (float*)d_ws;
    float* out = (float*)d_out;

    // zero the small atomic-accumulated strip (ksum, vsum, mg)
    (void)hipMemsetAsync((void*)(ws + KSUM_OFF),
                         0, (size_t)(BH*MM + BH*DD + 4) * sizeof(float), stream);
    keys_kernel<<<dim3(512), dim3(512), 0, stream>>>(k, v, p, ws, out);
    reduce_kernel<<<dim3(512), dim3(512), 0, stream>>>(out, ws);
    query_kernel<<<dim3(512), dim3(512), 0, stream>>>(q, p, ws, out);
}

// Round 14
// 140.147 us; speedup vs baseline: 1.2951x; 1.2951x over previous
//
#include <hip/hip_runtime.h>
#include <hip/hip_bf16.h>

// Performer FastAttention — MFMA bf16 (consistent bf16 rounding).
// Keys: PRODUCER/CONSUMER wave specialization — 2 producer waves stage k/vT/diag
// into double-buffered LDS (register-pipelined loads, raw lgkm-only barriers so
// global loads stay in flight); 8 consumer waves run S-GEMM -> exp -> repack ->
// ctx GEMM (r12 math, identical layouts). Partials to d_out + reduce.
// Query: single-pass unshifted-exp with eps-correction (unchanged).
// B=4,H=16 -> BH=64; N=4096; D=E=64; M=256.

#define BH    64
#define NSEQ  4096
#define DD    64
#define MM    256
#define DN    0.35355339059327373f   // 64^-0.25
#define RATIO 0.0625f                 // 256^-0.5
#define EPS   1e-4f
#define NSEG  8

// ws layout (float units) — proven 4.28 MB layout:
#define CTX_OFF  0                       // BH*MM*DD = 1,048,576
#define KSUM_OFF (BH*MM*DD)              // + BH*MM = 16,384
#define VSUM_OFF (KSUM_OFF + BH*MM)      // + BH*DD = 4,096
#define MG_OFF   (VSUM_OFF + BH*DD)      // + 4
#define CTX_SLICE (BH*MM*DD)             // per-seg partial slice (in d_out)

typedef __attribute__((ext_vector_type(8)))  short bf16x8;
typedef __attribute__((ext_vector_type(16))) float f32x16;

#define MFMA(a,b,c) __builtin_amdgcn_mfma_f32_32x32x16_bf16((a),(b),(c),0,0,0)
#define PATROW(r,h) ((((r)&3) + 8*((r)>>2)) + 4*(h))
// raw barrier: drain own LDS ops only; global loads stay in flight (no vmcnt!)
#define BARRIER() asm volatile("s_waitcnt lgkmcnt(0)\n\ts_barrier" ::: "memory")

__device__ __forceinline__ unsigned pkbf(float lo, float hi) {
    union { __hip_bfloat162 b2; unsigned u; } cvt;
    cvt.b2 = __float22bfloat162_rn(make_float2(lo, hi));
    return cvt.u;
}
__device__ __forceinline__ bf16x8 hi8(const float* x) {
    union { unsigned w[4]; bf16x8 v; } r;
    r.w[0] = pkbf(x[0], x[1]);
    r.w[1] = pkbf(x[2], x[3]);
    r.w[2] = pkbf(x[4], x[5]);
    r.w[3] = pkbf(x[6], x[7]);
    return r.v;
}
__device__ __forceinline__ unsigned ford(float f) {
    unsigned u = __float_as_uint(f);
    return (u & 0x80000000u) ? ~u : (u | 0x80000000u);
}
__device__ __forceinline__ float ford_inv(unsigned u) {
    return (u & 0x80000000u) ? __uint_as_float(u & 0x7fffffffu) : __uint_as_float(~u);
}
// C-layout tile (16 f32, rows = PATROW(r,h), col = l31) -> A-operand bf16 fragment.
template<int BASE>
__device__ __forceinline__ bf16x8 repack8(const f32x16& a, int h) {
    unsigned X0 = pkbf(a[BASE+0], a[BASE+1]);
    unsigned X1 = pkbf(a[BASE+2], a[BASE+3]);
    unsigned Y0 = pkbf(a[BASE+4], a[BASE+5]);
    unsigned Y1 = pkbf(a[BASE+6], a[BASE+7]);
    unsigned tX0 = (unsigned)__shfl_xor((int)X0, 32);
    unsigned tX1 = (unsigned)__shfl_xor((int)X1, 32);
    unsigned tY0 = (unsigned)__shfl_xor((int)Y0, 32);
    unsigned tY1 = (unsigned)__shfl_xor((int)Y1, 32);
    union { unsigned w[4]; bf16x8 v; } r;
    r.w[0] = h ? tY0 : X0;
    r.w[1] = h ? tY1 : X1;
    r.w[2] = h ? Y0 : tX0;
    r.w[3] = h ? Y1 : tX1;
    return r.v;
}

// ============================ KEYS ============================
// grid 512 = bh(64) x seg(8); block 640 = 8 consumer waves + 2 producer waves;
// 8 chunks x 64 k-rows, double-buffered LDS, one raw barrier per chunk.
__global__ __launch_bounds__(640, 1)
void keys_kernel(const float* __restrict__ kg, const float* __restrict__ vg,
                 const float* __restrict__ pg, float* __restrict__ ws,
                 float* __restrict__ outp)
{
    __shared__ __align__(16) short kf[2][64*64];   // dg-grouped (8 KB/buf)
    __shared__ __align__(16) short vT[2][64*64];   // [e][oct ^ swz(e)] (8 KB/buf)
    __shared__ float diagl[2][64];

    const int tid  = threadIdx.x;
    const int wv   = tid >> 6;
    const int lane = tid & 63;
    const int bh   = blockIdx.x >> 3;
    const int seg  = blockIdx.x & 7;

    if (wv < 8) {
        // ======================= CONSUMER =======================
        const int l31 = lane & 31;
        const int h   = lane >> 5;

        // proj B-fragments (col m = 32*wv + l31), DN folded, bf16
        bf16x8 pBh[4];
        {
            const int m = 32*wv + l31;
#pragma unroll
            for (int ks = 0; ks < 4; ++ks) {
                const int d0 = 16*ks + 8*h;
                float x[8];
                *(float4*)&x[0] = *(const float4*)(pg + m*64 + d0);
                *(float4*)&x[4] = *(const float4*)(pg + m*64 + d0 + 4);
#pragma unroll
                for (int i = 0; i < 8; ++i) x[i] *= DN;
                pBh[ks] = hi8(x);
            }
        }

        f32x16 cacc0, cacc1;
#pragma unroll
        for (int i = 0; i < 16; ++i) { cacc0[i] = 0.f; cacc1[i] = 0.f; }
        float ksacc = 0.f, mloc = -3e38f;

        BARRIER();   // buffer 0 staged

        for (int ch = 0; ch < 8; ++ch) {
            const int bc = ch & 1;

            // ---- S = D[n][m]: 8 MFMAs ----
            f32x16 s0, s1;
#pragma unroll
            for (int i = 0; i < 16; ++i) { s0[i] = 0.f; s1[i] = 0.f; }
            __builtin_amdgcn_s_setprio(1);
#pragma unroll
            for (int ks = 0; ks < 4; ++ks) {
                const int dg = ks*2 + h;
                const int ofs = dg*512 + ((l31*8) ^ (dg*8));
                bf16x8 a0 = *(const bf16x8*)&kf[bc][ofs];
                bf16x8 a1 = *(const bf16x8*)&kf[bc][ofs + 256];
                s0 = MFMA(a0, pBh[ks], s0);
                s1 = MFMA(a1, pBh[ks], s1);
            }
            __builtin_amdgcn_s_setprio(0);

            // ---- w = exp(S - diag), max/ksum ----
            {
                float kp = 0.f;
#pragma unroll
                for (int g = 0; g < 4; ++g) {
                    const float4 dq0 = *(const float4*)&diagl[bc][8*g + 4*h];
                    const float4 dq1 = *(const float4*)&diagl[bc][32 + 8*g + 4*h];
                    const float d0[4] = {dq0.x, dq0.y, dq0.z, dq0.w};
                    const float d1[4] = {dq1.x, dq1.y, dq1.z, dq1.w};
#pragma unroll
                    for (int j = 0; j < 4; ++j) {
                        const int r = 4*g + j;
                        mloc = fmaxf(mloc, s0[r]);
                        const float w0 = __expf(s0[r] - d0[j]);
                        s0[r] = w0; kp += w0;
                        mloc = fmaxf(mloc, s1[r]);
                        const float w1 = __expf(s1[r] - d1[j]);
                        s1[r] = w1; kp += w1;
                    }
                }
                ksacc += kp;
            }
            bf16x8 wfr[4];
            wfr[0] = repack8<0>(s0, h);
            wfr[1] = repack8<8>(s0, h);
            wfr[2] = repack8<0>(s1, h);
            wfr[3] = repack8<8>(s1, h);

            // ---- ctx GEMM: D[m][e] += w * v ----
            __builtin_amdgcn_s_setprio(1);
#pragma unroll
            for (int ks = 0; ks < 4; ++ks) {
                const int nb = 16*ks + 8*h;
                const int sw = 8*(l31 & 7);
                bf16x8 b0 = *(const bf16x8*)&vT[bc][l31*64      + (nb ^ sw)];
                bf16x8 b1 = *(const bf16x8*)&vT[bc][(l31+32)*64 + (nb ^ sw)];
                cacc0 = MFMA(wfr[ks], b0, cacc0);
                cacc1 = MFMA(wfr[ks], b1, cacc1);
            }
            __builtin_amdgcn_s_setprio(0);

            BARRIER();
        }

        // ---- consumer finals ----
        ksacc += __shfl_xor(ksacc, 32);
        if (h == 0) atomicAdd(&ws[KSUM_OFF + bh*MM + 32*wv + l31], ksacc);

#pragma unroll
        for (int m = 1; m <= 32; m <<= 1) mloc = fmaxf(mloc, __shfl_xor(mloc, m));
        if (lane == 0) atomicMax((unsigned*)&ws[MG_OFF], ford(mloc));

        {
            float* cb = outp + (size_t)(seg*BH + bh) * (MM*DD);
#pragma unroll
            for (int r = 0; r < 16; ++r) {
                const int m = 32*wv + PATROW(r, h);
                cb[m*64 + l31]      = cacc0[r];
                cb[m*64 + l31 + 32] = cacc1[r];
            }
        }
    } else {
        // ======================= PRODUCER (waves 8,9) =======================
        const int pt  = tid - 512;        // 0..127
        const int kn  = pt >> 1;          // k row 0..63
        const int dh  = pt & 1;           // k col-half
        const int ve  = pt & 63;          // v column
        const int vo0 = (pt >> 6) * 4;    // first row-octet (0 or 4)

        float kx[32], vx[32];
        float vsacc = 0.f;

        auto loads = [&](int ch) {
            const int rowb = bh*NSEQ + seg*512 + ch*64;
            const size_t kb = ((size_t)(rowb + kn))*64 + dh*32;
#pragma unroll
            for (int g = 0; g < 8; ++g)
                *(float4*)&kx[4*g] = *(const float4*)(kg + kb + 4*g);
            const size_t vb = ((size_t)(rowb + vo0*8))*64 + ve;
#pragma unroll
            for (int j = 0; j < 32; ++j)
                vx[j] = vg[vb + (size_t)j*64];
        };

        auto stage_write = [&](int b) {
            float ss = 0.f;
#pragma unroll
            for (int i = 0; i < 32; ++i) ss = fmaf(kx[i], kx[i], ss);
            ss += __shfl_xor(ss, 1);
            if (dh == 0) diagl[b][kn] = ss * 0.0625f;   // 0.5*DN^2 = 1/16
#pragma unroll
            for (int g = 0; g < 4; ++g) {
                const int dg = 4*dh + g;
                *(bf16x8*)&kf[b][dg*512 + ((kn*8) ^ (dg*8))] = hi8(&kx[8*g]);
            }
#pragma unroll
            for (int o = 0; o < 4; ++o) {
#pragma unroll
                for (int j = 0; j < 8; ++j) vsacc += vx[8*o + j];
                const int oct = vo0 + o;
                *(bf16x8*)&vT[b][ve*64 + ((oct*8) ^ (8*(ve & 7)))] = hi8(&vx[8*o]);
            }
        };

        loads(0);
        stage_write(0);
        loads(1);
        BARRIER();   // buffer 0 visible to consumers

        for (int ch = 0; ch < 8; ++ch) {
            if (ch < 7) {
                stage_write((ch + 1) & 1);   // regs hold chunk ch+1 data
                if (ch < 6) loads(ch + 2);   // stays in flight across BARRIER
            }
            BARRIER();
        }

        // ---- producer finals: vsum ----
        atomicAdd(&ws[VSUM_OFF + bh*DD + ve], vsacc);
    }
}

// ============================ REDUCE ============================
__global__ __launch_bounds__(512)
void reduce_kernel(const float* __restrict__ outp, float* __restrict__ ws)
{
    const int idx = blockIdx.x * 512 + threadIdx.x;
    const float4* o4 = (const float4*)outp;
    float4 s = o4[idx];
#pragma unroll
    for (int sl = 1; sl < NSEG; ++sl) {
        float4 t = o4[sl*(CTX_SLICE/4) + idx];
        s.x += t.x; s.y += t.y; s.z += t.z; s.w += t.w;
    }
    ((float4*)(ws + CTX_OFF))[idx] = s;
}

// ============================ QUERY ============================
// grid 512 = bh(64) x seg(8); block 512 = 8 waves; 2 chunks x 256 q-rows.
__global__ __launch_bounds__(512, 2)
void query_kernel(const float* __restrict__ qg, const float* __restrict__ pg,
                  const float* __restrict__ ws, float* __restrict__ out)
{
    __shared__ __align__(16) short pfh[MM*DD];      // DN-folded proj, frag-grouped
    __shared__ __align__(16) short ctxb[32*64*8];   // (ksg*2+h) x ecol x j
    __shared__ float ksuml[MM];
    __shared__ float ctxsuml[DD];
    __shared__ float ksumsuml;
    __shared__ float epsl[8][32];
    __shared__ float denl[8][32];

    const int tid  = threadIdx.x;
    const int wv   = tid >> 6;
    const int lane = tid & 63;
    const int l31  = lane & 31;
    const int h    = lane >> 5;
    const int bh   = blockIdx.x >> 3;
    const int seg  = blockIdx.x & 7;

    const float mg = ford_inv(*(const unsigned*)&ws[MG_OFF]);
    const float cs = RATIO * __expf(-mg);
    const float ce = RATIO * EPS;

    if (tid < DD) ctxsuml[tid] = 0.f;
    if (tid == 0) ksumsuml = 0.f;
    __syncthreads();

    // proj staging (DN folded) -> frag-grouped LDS
    {
        const int m = tid >> 1, dh = tid & 1;
#pragma unroll
        for (int b = 0; b < 4; ++b) {
            const int d0 = dh*32 + b*8;
            float x[8];
            *(float4*)&x[0] = *(const float4*)(pg + m*64 + d0);
            *(float4*)&x[4] = *(const float4*)(pg + m*64 + d0 + 4);
#pragma unroll
            for (int i = 0; i < 8; ++i) x[i] *= DN;
            const int g = ((m>>5)*4 + (d0>>4))*2 + ((d0>>3)&1);
            *(bf16x8*)&pfh[(g*32 + (m&31))*8] = hi8(x);
        }
    }
    // ctx staging: fold cs/ce, bf16, frag-grouped; accumulate ctxsum
#pragma unroll
    for (int it = 0; it < 4; ++it) {
        const int gid = it*512 + tid;
        const int g = gid >> 6, e = gid & 63;
        const int mb = (g>>1)*16 + (g&1)*8;
        const float vs = ws[VSUM_OFF + bh*DD + e];
        float part = 0.f;
        float xv[8];
#pragma unroll
        for (int j = 0; j < 8; ++j) {
            xv[j] = cs*ws[CTX_OFF + (size_t)bh*(MM*DD) + (mb+j)*64 + e] + ce*vs;
            part += xv[j];
        }
        *(bf16x8*)&ctxb[(g*64 + e)*8] = hi8(xv);
        atomicAdd(&ctxsuml[e], part);
    }
    // ksum (f32) + ksumsum
    if (tid < 256) {
        const float kt = cs*ws[KSUM_OFF + bh*MM + tid] + ce*(float)NSEQ;
        ksuml[tid] = kt;
        atomicAdd(&ksumsuml, kt);
    }
    __syncthreads();

    const float cs0 = ctxsuml[l31];
    const float cs1 = ctxsuml[l31 + 32];
    const float kss = ksumsuml;

    for (int ch = 0; ch < 2; ++ch) {
        const int rown = seg*512 + ch*256 + wv*32;
        const size_t gn = (size_t)(bh*NSEQ + rown + l31);

        // q straight from global (raw bf16); diag = ss/16
        bf16x8 qbh[4];
        float ss = 0.f;
#pragma unroll
        for (int ks = 0; ks < 4; ++ks) {
            const int d0 = 16*ks + 8*h;
            float x[8];
            *(float4*)&x[0] = *(const float4*)(qg + gn*64 + d0);
            *(float4*)&x[4] = *(const float4*)(qg + gn*64 + d0 + 4);
#pragma unroll
            for (int i = 0; i < 8; ++i) ss = fmaf(x[i], x[i], ss);
            qbh[ks] = hi8(x);
        }
        const float diag = (ss + __shfl_xor(ss, 32)) * 0.0625f;

        // ---- fused: S tile -> u=exp(S-diag) -> max/den -> repack -> num GEMM ----
        f32x16 n0, n1;
#pragma unroll
        for (int i = 0; i < 16; ++i) { n0[i] = 0.f; n1[i] = 0.f; }
        float den = 0.f, mx = -3e38f;
#pragma unroll
        for (int mt = 0; mt < 8; ++mt) {
            f32x16 s;
#pragma unroll
            for (int i = 0; i < 16; ++i) s[i] = 0.f;
#pragma unroll
            for (int ks = 0; ks < 4; ++ks) {
                const int g = (mt*4 + ks)*2 + h;
                bf16x8 ah = *(const bf16x8*)&pfh[(g*32 + l31)*8];
                s = MFMA(ah, qbh[ks], s);
            }
#pragma unroll
            for (int r = 0; r < 16; ++r) mx = fmaxf(mx, s[r]);
#pragma unroll
            for (int r = 0; r < 16; ++r) {
                const float u = __expf(s[r] - diag);
                s[r] = u;
                den = fmaf(u, ksuml[mt*32 + PATROW(r, h)], den);
            }
            bf16x8 t0 = repack8<0>(s, h);
            bf16x8 t1 = repack8<8>(s, h);
            const int g0 = 4*mt + h, g1 = 4*mt + 2 + h;
            n0 = MFMA(t0, *(const bf16x8*)&ctxb[(g0*64 + l31)*8],      n0);
            n1 = MFMA(t0, *(const bf16x8*)&ctxb[(g0*64 + l31 + 32)*8], n1);
            n0 = MFMA(t1, *(const bf16x8*)&ctxb[(g1*64 + l31)*8],      n0);
            n1 = MFMA(t1, *(const bf16x8*)&ctxb[(g1*64 + l31 + 32)*8], n1);
        }

        // combine h-halves for this lane's own row (col l31)
        mx  = fmaxf(mx, __shfl_xor(mx, 32));
        den += __shfl_xor(den, 32);
        const float epsp = EPS * __expf(mx);
        const float denf = den + epsp * kss;
        if (h == 0) { epsl[wv][l31] = epsp; denl[wv][l31] = denf; }
        asm volatile("s_waitcnt lgkmcnt(0)" ::: "memory");

        // out = (num + eps*e^m*ctxsum) / den
#pragma unroll
        for (int r = 0; r < 16; ++r) {
            const int nn = PATROW(r, h);
            const float e1  = epsl[wv][nn];
            const float rdn = 1.0f / denl[wv][nn];
            float* op = out + ((size_t)(bh*NSEQ + rown + nn))*64;
            op[l31]      = (n0[r] + e1*cs0) * rdn;
            op[l31 + 32] = (n1[r] + e1*cs1) * rdn;
        }
    }
}

extern "C" void kernel_launch(void* const* d_in, const int* in_sizes, int n_in,
                              void* d_out, int out_size, void* d_ws, size_t ws_size,
                              hipStream_t stream)
{
    const float* q = (const float*)d_in[0];
    const float* k = (const float*)d_in[1];
    const float* v = (const float*)d_in[2];
    const float* p = (const float*)d_in[3];
    float* ws  = (float*)d_ws;
    float* out = (float*)d_out;

    // zero the small atomic-accumulated strip (ksum, vsum, mg)
    (void)hipMemsetAsync((void*)(ws + KSUM_OFF),
                         0, (size_t)(BH*MM + BH*DD + 4) * sizeof(float), stream);
    keys_kernel<<<dim3(512), dim3(640), 0, stream>>>(k, v, p, ws, out);
    reduce_kernel<<<dim3(512), dim3(512), 0, stream>>>(out, ws);
    query_kernel<<<dim3(512), dim3(512), 0, stream>>>(q, p, ws, out);
}